// Round 8
// baseline (333.884 us; speedup 1.0000x reference)
//
#include <hip/hip_runtime.h>
#include <hip/hip_bf16.h>

typedef short short8 __attribute__((ext_vector_type(8)));
typedef float floatx4 __attribute__((ext_vector_type(4)));

// hardware RTNE f32->bf16 (lowers to v_cvt_pk_bf16_f32 pairs; don't hand-roll — m240)
__device__ __forceinline__ unsigned short f2bf(float f) {
    __hip_bfloat16 h = __float2bfloat16(f);
    unsigned short u;
    __builtin_memcpy(&u, &h, 2);
    return u;
}

__device__ __forceinline__ float bf2f(unsigned short h) {
    union { unsigned int u; float f; } v;
    v.u = ((unsigned int)h) << 16;
    return v.f;
}

template <typename T>
__device__ __forceinline__ T ldany(const void* p) {
    T v;
    __builtin_memcpy(&v, p, sizeof(T));
    return v;
}

#define TPW 5  // tiles (of 16 rows) per wave
#define WPB 8  // waves per block (512 threads)

// out[n][d] = x[n][d] + sum_t mask(sigmoid(x[n]·tok[t])) * tok[t][d]
// GEMM1 swapped (zT = Tok·X^T), 2-pass split precision: th·xh + th·xl = th·x
// (dropped cross term tl·x adds logit sigma ~1.1e-3; threshold-flip error
//  budgeted ~0.06-0.10 vs 0.143 threshold). LDS 32 KB -> 3 blocks/CU possible.
// C1 -> A2 fragment redistribution via __shfl (ds_bpermute).
// Cross-tile x prefetch pinned with sched_barrier(0): rounds 5/6 showed the
// scheduler sinks the prefetch loads to their uses when VALU work is cheap
// (VGPR 76->48, +30us). The barrier forbids moving the loads past it.
__global__ __launch_bounds__(512, 6) void fused_prompt(
    const float* __restrict__ X, const float* __restrict__ Tok,
    float* __restrict__ Out, int N)
{
    // token LDS, XOR-swizzled: element (row,col) at row*stride + (col ^ ((row&7)<<3))
    __shared__ unsigned short tokA[64 * 128];  // [t][d] hi  (GEMM1 A-operand)
    __shared__ unsigned short tokT[128 * 64];  // [d][t] hi  (GEMM2 B-operand)

    const int tid = threadIdx.x;

    // stage loop A: [t][d] layout; i -> consecutive d => conflict-free writes
    for (int i = tid; i < 64 * 128; i += 512) {
        const int t = i >> 7, d = i & 127;
        tokA[t * 128 + (d ^ ((t & 7) << 3))] = f2bf(Tok[i]);
    }
    // stage loop B: [d][t] layout; i -> consecutive t => conflict-free writes
    for (int i = tid; i < 64 * 128; i += 512) {
        const int t = i & 63, d = i >> 6;
        tokT[d * 64 + (t ^ ((d & 7) << 3))] = f2bf(Tok[t * 128 + d]);
    }
    __syncthreads();

    const int lane = tid & 63;
    const int wave = tid >> 6;
    const int ln = lane & 15;  // fragment row/col index
    const int q = lane >> 4;   // k-group

    const long baseTile = ((long)blockIdx.x * WPB + wave) * TPW;
    if (baseTile * 16 >= N) return;  // tail wave: no work (barrier already passed)

    // prologue: issue tile-0 x loads
    floatx4 xc[8];
    {
        const float* xr = X + (baseTile * 16 + ln) * 128;
#pragma unroll
        for (int u = 0; u < 4; ++u) {
            xc[2 * u] = ldany<floatx4>(xr + u * 32 + q * 8);
            xc[2 * u + 1] = ldany<floatx4>(xr + u * 32 + q * 8 + 4);
        }
    }

#pragma unroll
    for (int it = 0; it < TPW; ++it) {
        const long r0 = (baseTile + it) * 16;
        if (r0 >= N) return;  // tail guard

        // ---- prefetch next tile's x; sched_barrier pins the issue point ----
        floatx4 xn[8];
        if (it + 1 < TPW) {
            long pr = r0 + 16 + ln;
            if (pr >= N) pr = N - 1;  // clamp: last tiles must not read past X
            const float* xr = X + pr * 128;
#pragma unroll
            for (int u = 0; u < 4; ++u) {
                xn[2 * u] = ldany<floatx4>(xr + u * 32 + q * 8);
                xn[2 * u + 1] = ldany<floatx4>(xr + u * 32 + q * 8 + 4);
            }
        }
        __builtin_amdgcn_sched_barrier(0);  // prefetch loads may not sink below here

        // ---- convert current x slice to bf16 hi/lo fragments (hw cvt) ----
        short8 xbh[4], xbl[4];
#pragma unroll
        for (int ks = 0; ks < 4; ++ks) {
#pragma unroll
            for (int j = 0; j < 4; ++j) {
                const float v0 = xc[2 * ks][j], v1 = xc[2 * ks + 1][j];
                const unsigned short h0 = f2bf(v0), h1 = f2bf(v1);
                xbh[ks][j] = (short)h0;
                xbh[ks][j + 4] = (short)h1;
                xbl[ks][j] = (short)f2bf(v0 - bf2f(h0));
                xbl[ks][j + 4] = (short)f2bf(v1 - bf2f(h1));
            }
        }

        // ======== GEMM1 (swapped): zT[64 x 16] = Tok[64x128] · Xtile^T ========
        floatx4 acc1[4];
#pragma unroll
        for (int tg = 0; tg < 4; ++tg) acc1[tg] = {0.f, 0.f, 0.f, 0.f};

#pragma unroll
        for (int ks = 0; ks < 4; ++ks) {
            const int d0 = ks * 32 + q * 8;
#pragma unroll
            for (int tg = 0; tg < 4; ++tg) {
                const int t = tg * 16 + ln;  // t&7 == ln&7
                const short8 ah = ldany<short8>(&tokA[t * 128 + (d0 ^ ((ln & 7) << 3))]);
                acc1[tg] = __builtin_amdgcn_mfma_f32_16x16x32_bf16(ah, xbh[ks], acc1[tg], 0, 0, 0);
                acc1[tg] = __builtin_amdgcn_mfma_f32_16x16x32_bf16(ah, xbl[ks], acc1[tg], 0, 0, 0);
            }
        }

        // ---- sigmoid + threshold mask; pack to bf16 pairs (hw cvt) ----
        // C1-swapped layout: lane (ln,q) holds z[t = tg*16 + q*4 + p][n = r0 + ln]
        unsigned int S[4][2];
#pragma unroll
        for (int tg = 0; tg < 4; ++tg) {
            unsigned short b[4];
#pragma unroll
            for (int p = 0; p < 4; ++p) {
                const float z = acc1[tg][p];
                const float e = __builtin_amdgcn_exp2f(z * -1.442695040888963f);
                float w = __builtin_amdgcn_rcpf(1.0f + e);
                if (w < 0.2f) w = 0.0f;
                b[p] = f2bf(w);
            }
            S[tg][0] = (unsigned)b[0] | ((unsigned)b[1] << 16);
            S[tg][1] = (unsigned)b[2] | ((unsigned)b[3] << 16);
        }

        // ---- epilogue x re-read; pin issue before shuffle+GEMM2 for latency cover ----
        float xadd[8][4];
#pragma unroll
        for (int p = 0; p < 4; ++p) {
            const float* xr = X + (r0 + q * 4 + p) * 128 + ln;
#pragma unroll
            for (int dg = 0; dg < 8; ++dg) xadd[dg][p] = xr[dg * 16];
        }
        __builtin_amdgcn_sched_barrier(0);  // xadd loads may not sink below here

        // ---- C1 -> A2 fragment shuffle via __shfl ----
        // target: a2[k2] elem j = W[n=ln][t = 32k2 + 8q + j]
        // source word for (k2,q,w): tg = 2k2+(q>>1), q_src = 2(q&1)+(w>>1), wi = w&1
        union {
            unsigned int u[4];
            short8 s;
        } a2[2];
#pragma unroll
        for (int k2 = 0; k2 < 2; ++k2) {
#pragma unroll
            for (int w = 0; w < 4; ++w) {
                const int srcLane = ln + 16 * (2 * (q & 1) + (w >> 1));
                const int lo = __shfl((int)S[2 * k2][w & 1], srcLane, 64);
                const int hi = __shfl((int)S[2 * k2 + 1][w & 1], srcLane, 64);
                a2[k2].u[w] = (unsigned int)((q < 2) ? lo : hi);
            }
        }

        // ======== GEMM2: out[16 x 128] = W[16x64] · Tok[64x128] ========
        floatx4 acc2[8];
#pragma unroll
        for (int dg = 0; dg < 8; ++dg) acc2[dg] = {0.f, 0.f, 0.f, 0.f};

#pragma unroll
        for (int k2 = 0; k2 < 2; ++k2) {
            const int t0 = k2 * 32 + q * 8;
#pragma unroll
            for (int dg = 0; dg < 8; ++dg) {
                const int d = dg * 16 + ln;  // d&7 == ln&7
                const short8 b2 = ldany<short8>(&tokT[d * 64 + (t0 ^ ((ln & 7) << 3))]);
                acc2[dg] = __builtin_amdgcn_mfma_f32_16x16x32_bf16(a2[k2].s, b2, acc2[dg], 0, 0, 0);
            }
        }

        // ---- add x, store ----
#pragma unroll
        for (int p = 0; p < 4; ++p) {
            float* orow = Out + (r0 + q * 4 + p) * 128 + ln;
#pragma unroll
            for (int dg = 0; dg < 8; ++dg) orow[dg * 16] = acc2[dg][p] + xadd[dg][p];
        }

        // ---- rotate prefetch buffer ----
        if (it + 1 < TPW) {
#pragma unroll
            for (int u = 0; u < 8; ++u) xc[u] = xn[u];
        }
    }
}

extern "C" void kernel_launch(void* const* d_in, const int* in_sizes, int n_in,
                              void* d_out, int out_size, void* d_ws, size_t ws_size,
                              hipStream_t stream) {
    const float* X = (const float*)d_in[0];
    const float* Tok = (const float*)d_in[1];
    float* Out = (float*)d_out;
    const int N = in_sizes[0] / 128;                           // 1,000,000
    const int tiles = (N + 15) / 16;                           // 62,500
    const int blocks = (tiles + WPB * TPW - 1) / (WPB * TPW);  // 1,563
    fused_prompt<<<blocks, 512, 0, stream>>>(X, Tok, Out, N);
}

// Round 9
// 247.192 us; speedup vs baseline: 1.3507x; 1.3507x over previous
//
#include <hip/hip_runtime.h>
#include <hip/hip_bf16.h>

typedef short short8 __attribute__((ext_vector_type(8)));
typedef float floatx4 __attribute__((ext_vector_type(4)));

// hardware RTNE f32->bf16 (lowers to v_cvt_pk_bf16_f32 pairs; don't hand-roll — m240)
__device__ __forceinline__ unsigned short f2bf(float f) {
    __hip_bfloat16 h = __float2bfloat16(f);
    unsigned short u;
    __builtin_memcpy(&u, &h, 2);
    return u;
}

__device__ __forceinline__ float bf2f(unsigned short h) {
    union { unsigned int u; float f; } v;
    v.u = ((unsigned int)h) << 16;
    return v.f;
}

template <typename T>
__device__ __forceinline__ T ldany(const void* p) {
    T v;
    __builtin_memcpy(&v, p, sizeof(T));
    return v;
}

#define TPW 5  // tiles (of 16 rows) per wave
#define WPB 8  // waves per block (512 threads)

// out[n][d] = x[n][d] + sum_t mask(sigmoid(x[n]·tok[t])) * tok[t][d]
// GEMM1 swapped (zT = Tok·X^T), 2-pass split precision: th·xh + th·xl = th·x
// (absmax 0.094 vs 0.143 threshold — round-8 verified).
// C1 -> A2 fragment redistribution via __shfl (ds_bpermute).
// Cross-tile x prefetch pinned with sched_barrier(0) (rounds 5-7: scheduler
// sinks prefetch loads when VALU work is cheap; barrier forbids it).
// launch_bounds(512,4): round 8 showed (512,6) caps VGPR ~85 -> spills the
// prefetch/acc working set to scratch (+400MB HBM traffic, +87us). 4 waves/EU
// (VGPR<=128) fits the ~76-reg working set with zero spill.
__global__ __launch_bounds__(512, 4) void fused_prompt(
    const float* __restrict__ X, const float* __restrict__ Tok,
    float* __restrict__ Out, int N)
{
    // token LDS, XOR-swizzled: element (row,col) at row*stride + (col ^ ((row&7)<<3))
    __shared__ unsigned short tokA[64 * 128];  // [t][d] hi  (GEMM1 A-operand)
    __shared__ unsigned short tokT[128 * 64];  // [d][t] hi  (GEMM2 B-operand)

    const int tid = threadIdx.x;

    // stage loop A: [t][d] layout; i -> consecutive d => conflict-free writes
    for (int i = tid; i < 64 * 128; i += 512) {
        const int t = i >> 7, d = i & 127;
        tokA[t * 128 + (d ^ ((t & 7) << 3))] = f2bf(Tok[i]);
    }
    // stage loop B: [d][t] layout; i -> consecutive t => conflict-free writes
    for (int i = tid; i < 64 * 128; i += 512) {
        const int t = i & 63, d = i >> 6;
        tokT[d * 64 + (t ^ ((d & 7) << 3))] = f2bf(Tok[t * 128 + d]);
    }
    __syncthreads();

    const int lane = tid & 63;
    const int wave = tid >> 6;
    const int ln = lane & 15;  // fragment row/col index
    const int q = lane >> 4;   // k-group

    const long baseTile = ((long)blockIdx.x * WPB + wave) * TPW;
    if (baseTile * 16 >= N) return;  // tail wave: no work (barrier already passed)

    // prologue: issue tile-0 x loads
    floatx4 xc[8];
    {
        const float* xr = X + (baseTile * 16 + ln) * 128;
#pragma unroll
        for (int u = 0; u < 4; ++u) {
            xc[2 * u] = ldany<floatx4>(xr + u * 32 + q * 8);
            xc[2 * u + 1] = ldany<floatx4>(xr + u * 32 + q * 8 + 4);
        }
    }

#pragma unroll
    for (int it = 0; it < TPW; ++it) {
        const long r0 = (baseTile + it) * 16;
        if (r0 >= N) return;  // tail guard

        // ---- prefetch next tile's x; sched_barrier pins the issue point ----
        floatx4 xn[8];
        if (it + 1 < TPW) {
            long pr = r0 + 16 + ln;
            if (pr >= N) pr = N - 1;  // clamp: last tiles must not read past X
            const float* xr = X + pr * 128;
#pragma unroll
            for (int u = 0; u < 4; ++u) {
                xn[2 * u] = ldany<floatx4>(xr + u * 32 + q * 8);
                xn[2 * u + 1] = ldany<floatx4>(xr + u * 32 + q * 8 + 4);
            }
        }
        __builtin_amdgcn_sched_barrier(0);  // prefetch loads may not sink below here

        // ---- convert current x slice to bf16 hi/lo fragments (hw cvt) ----
        short8 xbh[4], xbl[4];
#pragma unroll
        for (int ks = 0; ks < 4; ++ks) {
#pragma unroll
            for (int j = 0; j < 4; ++j) {
                const float v0 = xc[2 * ks][j], v1 = xc[2 * ks + 1][j];
                const unsigned short h0 = f2bf(v0), h1 = f2bf(v1);
                xbh[ks][j] = (short)h0;
                xbh[ks][j + 4] = (short)h1;
                xbl[ks][j] = (short)f2bf(v0 - bf2f(h0));
                xbl[ks][j + 4] = (short)f2bf(v1 - bf2f(h1));
            }
        }

        // ======== GEMM1 (swapped): zT[64 x 16] = Tok[64x128] · Xtile^T ========
        floatx4 acc1[4];
#pragma unroll
        for (int tg = 0; tg < 4; ++tg) acc1[tg] = {0.f, 0.f, 0.f, 0.f};

#pragma unroll
        for (int ks = 0; ks < 4; ++ks) {
            const int d0 = ks * 32 + q * 8;
#pragma unroll
            for (int tg = 0; tg < 4; ++tg) {
                const int t = tg * 16 + ln;  // t&7 == ln&7
                const short8 ah = ldany<short8>(&tokA[t * 128 + (d0 ^ ((ln & 7) << 3))]);
                acc1[tg] = __builtin_amdgcn_mfma_f32_16x16x32_bf16(ah, xbh[ks], acc1[tg], 0, 0, 0);
                acc1[tg] = __builtin_amdgcn_mfma_f32_16x16x32_bf16(ah, xbl[ks], acc1[tg], 0, 0, 0);
            }
        }

        // ---- sigmoid + threshold mask; pack to bf16 pairs (hw cvt) ----
        // C1-swapped layout: lane (ln,q) holds z[t = tg*16 + q*4 + p][n = r0 + ln]
        unsigned int S[4][2];
#pragma unroll
        for (int tg = 0; tg < 4; ++tg) {
            unsigned short b[4];
#pragma unroll
            for (int p = 0; p < 4; ++p) {
                const float z = acc1[tg][p];
                const float e = __builtin_amdgcn_exp2f(z * -1.442695040888963f);
                float w = __builtin_amdgcn_rcpf(1.0f + e);
                if (w < 0.2f) w = 0.0f;
                b[p] = f2bf(w);
            }
            S[tg][0] = (unsigned)b[0] | ((unsigned)b[1] << 16);
            S[tg][1] = (unsigned)b[2] | ((unsigned)b[3] << 16);
        }

        // ---- epilogue x re-read; pin issue before shuffle+GEMM2 for latency cover ----
        float xadd[8][4];
#pragma unroll
        for (int p = 0; p < 4; ++p) {
            const float* xr = X + (r0 + q * 4 + p) * 128 + ln;
#pragma unroll
            for (int dg = 0; dg < 8; ++dg) xadd[dg][p] = xr[dg * 16];
        }
        __builtin_amdgcn_sched_barrier(0);  // xadd loads may not sink below here

        // ---- C1 -> A2 fragment shuffle via __shfl ----
        // target: a2[k2] elem j = W[n=ln][t = 32k2 + 8q + j]
        // source word for (k2,q,w): tg = 2k2+(q>>1), q_src = 2(q&1)+(w>>1), wi = w&1
        union {
            unsigned int u[4];
            short8 s;
        } a2[2];
#pragma unroll
        for (int k2 = 0; k2 < 2; ++k2) {
#pragma unroll
            for (int w = 0; w < 4; ++w) {
                const int srcLane = ln + 16 * (2 * (q & 1) + (w >> 1));
                const int lo = __shfl((int)S[2 * k2][w & 1], srcLane, 64);
                const int hi = __shfl((int)S[2 * k2 + 1][w & 1], srcLane, 64);
                a2[k2].u[w] = (unsigned int)((q < 2) ? lo : hi);
            }
        }

        // ======== GEMM2: out[16 x 128] = W[16x64] · Tok[64x128] ========
        floatx4 acc2[8];
#pragma unroll
        for (int dg = 0; dg < 8; ++dg) acc2[dg] = {0.f, 0.f, 0.f, 0.f};

#pragma unroll
        for (int k2 = 0; k2 < 2; ++k2) {
            const int t0 = k2 * 32 + q * 8;
#pragma unroll
            for (int dg = 0; dg < 8; ++dg) {
                const int d = dg * 16 + ln;  // d&7 == ln&7
                const short8 b2 = ldany<short8>(&tokT[d * 64 + (t0 ^ ((ln & 7) << 3))]);
                acc2[dg] = __builtin_amdgcn_mfma_f32_16x16x32_bf16(a2[k2].s, b2, acc2[dg], 0, 0, 0);
            }
        }

        // ---- add x, store ----
#pragma unroll
        for (int p = 0; p < 4; ++p) {
            float* orow = Out + (r0 + q * 4 + p) * 128 + ln;
#pragma unroll
            for (int dg = 0; dg < 8; ++dg) orow[dg * 16] = acc2[dg][p] + xadd[dg][p];
        }

        // ---- rotate prefetch buffer ----
        if (it + 1 < TPW) {
#pragma unroll
            for (int u = 0; u < 8; ++u) xc[u] = xn[u];
        }
    }
}

extern "C" void kernel_launch(void* const* d_in, const int* in_sizes, int n_in,
                              void* d_out, int out_size, void* d_ws, size_t ws_size,
                              hipStream_t stream) {
    const float* X = (const float*)d_in[0];
    const float* Tok = (const float*)d_in[1];
    float* Out = (float*)d_out;
    const int N = in_sizes[0] / 128;                           // 1,000,000
    const int tiles = (N + 15) / 16;                           // 62,500
    const int blocks = (tiles + WPB * TPW - 1) / (WPB * TPW);  // 1,563
    fused_prompt<<<blocks, 512, 0, stream>>>(X, Tok, Out, N);
}